// Round 14
// baseline (358.128 us; speedup 1.0000x reference)
//
#include <hip/hip_runtime.h>
#include <hip/hip_bf16.h>
#include <hip/hip_fp16.h>

#define NN    10000
#define FIN   512
#define FOUT  256
#define NPAD  10240
#define LRA   0.2f
#define NSL   16          // slices; id%16 -> 2 slices/XCD, B L2-resident
#define JLEN  640         // NPAD / NSL
#define NPH   10          // JLEN / 64
#define WPR32 320         // u32 words per row (LINEAR layout: word=j/32, bit=j%32)

typedef __attribute__((ext_vector_type(4))) float    f32x4;
typedef __attribute__((ext_vector_type(4))) int      i32x4;
typedef __attribute__((ext_vector_type(4))) short    s16x4;
typedef __attribute__((ext_vector_type(8))) _Float16 f16x8;
typedef __attribute__((ext_vector_type(8))) short    bf16x8;

static __device__ __forceinline__ short f2bf(float x) {
  unsigned u = __builtin_bit_cast(unsigned, x);
  u += 0x7fffu + ((u >> 16) & 1u);   // RNE; x always finite here
  return (short)(u >> 16);
}
static __device__ __forceinline__ float bf2f(short s) {
  unsigned u = ((unsigned)(unsigned short)s) << 16;
  return __builtin_bit_cast(float, u);
}

// ---------------- K0: Wt[c][k] = f16(W[k][c]) ----------------
__global__ __launch_bounds__(256) void k0_wt(const float* __restrict__ W,
                                             _Float16* __restrict__ Wt) {
  int idx = blockIdx.x * 256 + threadIdx.x;
  int k = idx >> 8, c = idx & 255;
  Wt[(size_t)c * FIN + k] = (_Float16)W[(size_t)k * FOUT + c];
}

// ---------------- K12: fused Wh(regs) -> LDS -> e1/e2 + WhT ----------------
// k1's MFMA (Wh in acc) + k2's epilogue from an LDS tile; Wh never hits HBM.
__global__ __launch_bounds__(256) void k12_fused(const float* __restrict__ h,
                                                 const _Float16* __restrict__ Wt,
                                                 const float* __restrict__ a,
                                                 float* __restrict__ e1,
                                                 float* __restrict__ e2,
                                                 short* __restrict__ WhT) {
  __shared__ float tile[64][257];
  const int r0 = blockIdx.x * 64;
  const int t = threadIdx.x;
  const int w = t >> 6, l = t & 63;
  const int lr = l & 15, lq = l >> 4;
  f32x4 acc[4][4];
#pragma unroll
  for (int m = 0; m < 4; ++m)
#pragma unroll
    for (int n = 0; n < 4; ++n)
#pragma unroll
      for (int q = 0; q < 4; ++q) acc[m][n][q] = 0.f;

  for (int kk = 0; kk < FIN; kk += 32) {
    f16x8 af[4];
#pragma unroll
    for (int m = 0; m < 4; ++m) {
      int gr = r0 + m * 16 + lr;
      if (gr < NN) {
        const f32x4* p = (const f32x4*)(h + (size_t)gr * FIN + kk + lq * 8);
        f32x4 v0 = p[0], v1 = p[1];
#pragma unroll
        for (int i = 0; i < 4; ++i) { af[m][i] = (_Float16)v0[i]; af[m][i + 4] = (_Float16)v1[i]; }
      } else {
#pragma unroll
        for (int i = 0; i < 8; ++i) af[m][i] = (_Float16)0.f;
      }
    }
#pragma unroll
    for (int n = 0; n < 4; ++n) {
      int gc = w * 64 + n * 16 + lr;
      f16x8 bf = *(const f16x8*)(Wt + (size_t)gc * FIN + kk + lq * 8);
#pragma unroll
      for (int m = 0; m < 4; ++m)
        acc[m][n] = __builtin_amdgcn_mfma_f32_16x16x32_f16(af[m], bf, acc[m][n], 0, 0, 0);
    }
  }
  // acc -> LDS tile
#pragma unroll
  for (int m = 0; m < 4; ++m)
#pragma unroll
    for (int n = 0; n < 4; ++n)
#pragma unroll
      for (int q = 0; q < 4; ++q)
        tile[m * 16 + lq * 4 + q][w * 64 + n * 16 + lr] = acc[m][n][q];
  __syncthreads();
  // e1/e2 from LDS
  {
    int r = t >> 2, sub = t & 3;
    float s1 = 0.f, s2 = 0.f;
#pragma unroll
    for (int i = 0; i < 64; ++i) {
      int c = sub + 4 * i;
      float v = tile[r][c];
      s1 += v * a[c];
      s2 += v * a[FOUT + c];
    }
    s1 += __shfl_xor(s1, 1); s1 += __shfl_xor(s1, 2);
    s2 += __shfl_xor(s2, 1); s2 += __shfl_xor(s2, 2);
    if (sub == 0) { e1[r0 + r] = s1; e2[r0 + r] = s2; }   // pad rows: tile==0 -> 0
  }
  // WhT from LDS
#pragma unroll
  for (int c0 = 0; c0 < FOUT; c0 += 64)
#pragma unroll
    for (int i = 0; i < 16; ++i) {
      int e = t + 256 * i;
      int c = e >> 6, rr = e & 63;
      WhT[(size_t)(c0 + c) * NPAD + r0 + rr] = f2bf(tile[rr][c0 + c]);
    }
}

// ---------------- KP: bit-pack adj — persistent grid-stride, double-buffered,
// non-temporal loads (read-once; keeps WhT L2-resident for k3) ----------------
#define KP_LOADW(G, V, F)                                                     \
  {                                                                           \
    int row_ = (G) / WPR32, wc_ = (G) - row_ * WPR32, j0_ = wc_ * 32;         \
    F = (row_ < NN) && (j0_ + 32 <= NN);                                      \
    if (F) {                                                                  \
      const i32x4* p_ = (const i32x4*)(adj + (size_t)row_ * NN + j0_);        \
      _Pragma("unroll")                                                       \
      for (int q_ = 0; q_ < 8; ++q_) V[q_] = __builtin_nontemporal_load(p_ + q_); \
    }                                                                         \
  }

#define KP_STOREW(G, V, F)                                                    \
  {                                                                           \
    unsigned m_ = 0u;                                                         \
    if (F) {                                                                  \
      _Pragma("unroll")                                                       \
      for (int q_ = 0; q_ < 8; ++q_)                                          \
        _Pragma("unroll")                                                     \
        for (int i_ = 0; i_ < 4; ++i_)                                        \
          m_ |= (V[q_][i_] > 0 ? 1u : 0u) << (q_ * 4 + i_);                   \
    } else {                                                                  \
      int row_ = (G) / WPR32, wc_ = (G) - row_ * WPR32, j0_ = wc_ * 32;       \
      if (row_ < NN && j0_ < NN) {                                            \
        const int* p_ = adj + (size_t)row_ * NN + j0_;                        \
        int nv_ = NN - j0_; if (nv_ > 32) nv_ = 32;                           \
        for (int k_ = 0; k_ < nv_; ++k_) m_ |= (p_[k_] > 0 ? 1u : 0u) << k_;  \
      }                                                                       \
    }                                                                         \
    bits32[G] = m_;                                                           \
  }

__global__ __launch_bounds__(256) void kp_bits(const int* __restrict__ adj,
                                               unsigned* __restrict__ bits32) {
  const int TOT = NPAD * WPR32;                    // 3,276,800
  const int nthr = gridDim.x * 256;
  int g0 = blockIdx.x * 256 + threadIdx.x;
  if (g0 >= TOT) return;
  i32x4 vA[8], vB[8];
  bool fA, fB;
  KP_LOADW(g0, vA, fA);
  while (true) {
    int g1 = g0 + nthr;
    bool has1 = g1 < TOT;
    if (has1) KP_LOADW(g1, vB, fB);
    KP_STOREW(g0, vA, fA);
    if (!has1) break;
    int g2 = g1 + nthr;
    bool has2 = g2 < TOT;
    if (has2) KP_LOADW(g2, vA, fA);
    KP_STOREW(g1, vB, fB);
    if (!has2) break;
    g0 = g2;
  }
}

// ---------------- K3: partial masked-softmax @ Wh (R13 structure) ----------
#define MFMA_B(AV, BV, ACC) ACC = __builtin_amdgcn_mfma_f32_16x16x32_bf16(AV, BV, ACC, 0, 0, 0)

#define B_ISSUE(PH)                                                           \
  {                                                                           \
    const int jg_ = jbase + (PH) * 64 + lq * 8;                               \
    bv00 = *(const bf16x8*)(WhT + bcol0 + jg_);                               \
    bv01 = *(const bf16x8*)(WhT + bcol1 + jg_);                               \
    bv10 = *(const bf16x8*)(WhT + bcol0 + jg_ + 32);                          \
    bv11 = *(const bf16x8*)(WhT + bcol1 + jg_ + 32);                          \
  }

#define PRODUCE(PH)                                                           \
  {                                                                           \
    const int jl_ = (PH) * 64 + sub * 16;                                     \
    f32x4 ea = *(const f32x4*)(e2s + jl_);                                    \
    f32x4 eb = *(const f32x4*)(e2s + jl_ + 4);                                \
    f32x4 ec = *(const f32x4*)(e2s + jl_ + 8);                                \
    f32x4 ed = *(const f32x4*)(e2s + jl_ + 12);                               \
    const unsigned m16 = mk[(PH) >> 1] >> (((PH) & 1) * 16);                  \
    bf16x8 pf0, pf1;                                                          \
    _Pragma("unroll")                                                         \
    for (int i = 0; i < 16; ++i) {                                            \
      float x = e1v + ((i < 4) ? ea[i & 3] : (i < 8) ? eb[i & 3]              \
                       : (i < 12) ? ec[i & 3] : ed[i & 3]);                   \
      float sv = fmaxf(x, LRA * x);                                           \
      float p = ((m16 >> i) & 1u) ? __expf(sv) : 0.f;                         \
      rs += p;                                                                \
      if (i < 8) pf0[i] = f2bf(p); else pf1[i & 7] = f2bf(p);                 \
    }                                                                         \
    char* wb_ = &Plds[(PH) & 1][0] + prow * 128;                              \
    *(bf16x8*)(wb_ + ((sub * 32) ^ psw)) = pf0;                               \
    *(bf16x8*)(wb_ + ((sub * 32 + 16) ^ psw)) = pf1;                          \
  }

#define CONSUME(PH)                                                           \
  {                                                                           \
    const char* pb_ = &Plds[(PH) & 1][0];                                     \
    __builtin_amdgcn_s_setprio(1);                                            \
    _Pragma("unroll")                                                         \
    for (int kt = 0; kt < 2; ++kt) {                                          \
      const int ao_ = (kt * 64 + lq * 16) ^ axor;                             \
      _Pragma("unroll")                                                       \
      for (int m = 0; m < 8; ++m) {                                           \
        bf16x8 av = *(const bf16x8*)(pb_ + m * 2048 + lr * 128 + ao_);        \
        MFMA_B(av, (kt ? bv10 : bv00), acc[m][0]);                            \
        MFMA_B(av, (kt ? bv11 : bv01), acc[m][1]);                            \
      }                                                                       \
    }                                                                         \
    __builtin_amdgcn_s_setprio(0);                                            \
  }

#define K3_ITER(PH)                                                           \
  __syncthreads();                                                            \
  B_ISSUE(PH);                                                                \
  PRODUCE((PH) + 1);                                                          \
  CONSUME(PH);

__global__ __launch_bounds__(512, 2) void k3_part(const unsigned* __restrict__ bits32,
                                                  const float* __restrict__ e1,
                                                  const float* __restrict__ e2,
                                                  const short* __restrict__ WhT,
                                                  short* __restrict__ pnum,
                                                  float* __restrict__ pden) {
  __shared__ __align__(16) char Plds[2][16384];   // [128 r][64 j] bf16, XOR-swizzled
  __shared__ float e2s[JLEN];
  const int id = blockIdx.x;
  const int s = id & (NSL - 1);
  const int r0 = (id >> 4) * 128;
  const int jbase = s * JLEN;
  const int t = threadIdx.x;
  const int w = t >> 6, l = t & 63;
  const int lr = l & 15, lq = l >> 4;
  const int prow = t >> 2, sub = t & 3;           // producer: 4 thr/row, 16 j each
  const int psw = (prow & 7) << 4;
  const int axor = (lr & 7) << 4;
  const int grow = r0 + prow;
  const float e1v = e1[grow];
  const size_t bcol0 = (size_t)(w * 32 + lr) * NPAD;
  const size_t bcol1 = bcol0 + (size_t)16 * NPAD;

  if (t < JLEN / 4) ((f32x4*)e2s)[t] = ((const f32x4*)(e2 + jbase))[t];

  unsigned mk[NPH / 2];
  {
    const unsigned* br = bits32 + (size_t)grow * WPR32 + (jbase >> 5) + (sub >> 1);
    const int hs = (sub & 1) * 16;
#pragma unroll
    for (int ph = 0; ph < NPH; ++ph) {
      unsigned m16 = (br[ph * 2] >> hs) & 0xFFFFu;
      if (ph & 1) mk[ph >> 1] |= m16 << 16; else mk[ph >> 1] = m16;
    }
  }

  f32x4 acc[8][2];
#pragma unroll
  for (int m = 0; m < 8; ++m)
#pragma unroll
    for (int n = 0; n < 2; ++n)
#pragma unroll
      for (int q = 0; q < 4; ++q) acc[m][n][q] = 0.f;
  float rs = 0.f;
  bf16x8 bv00, bv01, bv10, bv11;

  __syncthreads();                                 // e2s ready
  PRODUCE(0);
  K3_ITER(0) K3_ITER(1) K3_ITER(2) K3_ITER(3) K3_ITER(4)
  K3_ITER(5) K3_ITER(6) K3_ITER(7) K3_ITER(8)
  __syncthreads();
  B_ISSUE(9);
  CONSUME(9);

  rs += __shfl_xor(rs, 1); rs += __shfl_xor(rs, 2);
  if (sub == 0) pden[(size_t)s * NPAD + grow] = rs;
  {
    short* po = pnum + ((size_t)s * NPAD + r0) * FOUT;
#pragma unroll
    for (int m = 0; m < 8; ++m)
#pragma unroll
      for (int n = 0; n < 2; ++n)
#pragma unroll
        for (int q = 0; q < 4; ++q) {
          int row = m * 16 + lq * 4 + q;
          po[(size_t)row * FOUT + w * 32 + n * 16 + lr] = f2bf(acc[m][n][q]);
        }
  }
}

// ---------------- K4: reduce slices, normalize, elu (short4 loads) ----------
__global__ __launch_bounds__(256) void k4_out(const short* __restrict__ pnum,
                                              const float* __restrict__ pden,
                                              float* __restrict__ out) {
  const int t = threadIdx.x;
  const int row = blockIdx.x * 4 + (t >> 6);      // grid 2500, 4 rows/block
  const int c4 = (t & 63) * 4;
  float den = 0.f;
#pragma unroll
  for (int s = 0; s < NSL; ++s) den += pden[(size_t)s * NPAD + row];
  float n0 = 0.f, n1 = 0.f, n2 = 0.f, n3 = 0.f;
#pragma unroll
  for (int s = 0; s < NSL; ++s) {
    s16x4 v = *(const s16x4*)(pnum + ((size_t)s * NPAD + row) * FOUT + c4);
    n0 += bf2f(v[0]); n1 += bf2f(v[1]); n2 += bf2f(v[2]); n3 += bf2f(v[3]);
  }
  const float inv = 1.f / den;
  f32x4 o;
  float v0 = n0 * inv; o[0] = (v0 > 0.f) ? v0 : (__expf(v0) - 1.f);
  float v1 = n1 * inv; o[1] = (v1 > 0.f) ? v1 : (__expf(v1) - 1.f);
  float v2 = n2 * inv; o[2] = (v2 > 0.f) ? v2 : (__expf(v2) - 1.f);
  float v3 = n3 * inv; o[3] = (v3 > 0.f) ? v3 : (__expf(v3) - 1.f);
  *(f32x4*)(out + (size_t)row * FOUT + c4) = o;
}

// ---------------- Fallback (ws too small): R2 fused k3 ----------------
#define OLD_LOAD(J0N, AV, EV)                                               \
  {                                                                         \
    const int jn_ = (J0N) + jb;                                             \
    EV[0] = *(const f32x4*)(e2 + jn_);                                      \
    EV[1] = *(const f32x4*)(e2 + jn_ + 4);                                  \
    EV[2] = *(const f32x4*)(e2 + jn_ + 128);                                \
    EV[3] = *(const f32x4*)(e2 + jn_ + 132);                                \
    if (rowok && (J0N) + 256 <= NN) {                                       \
      AV[0] = *(const i32x4*)(adj + adjrow + jn_);                          \
      AV[1] = *(const i32x4*)(adj + adjrow + jn_ + 4);                      \
      AV[2] = *(const i32x4*)(adj + adjrow + jn_ + 128);                    \
      AV[3] = *(const i32x4*)(adj + adjrow + jn_ + 132);                    \
    } else {                                                                \
      _Pragma("unroll")                                                     \
      for (int p_ = 0; p_ < 4; ++p_) {                                      \
        _Pragma("unroll")                                                   \
        for (int i_ = 0; i_ < 4; ++i_) {                                    \
          int j_ = jn_ + (p_ >> 1) * 128 + (p_ & 1) * 4 + i_;               \
          AV[p_][i_] = (rowok && j_ < NN) ? adj[adjrow + j_] : 0;           \
        }                                                                   \
      }                                                                     \
    }                                                                       \
  }

#define OLD_PHASE(J0, AV, EV, BUF)                                          \
  {                                                                         \
    bf16x8 pf0, pf1;                                                        \
    _Pragma("unroll")                                                       \
    for (int i = 0; i < 8; ++i) {                                           \
      float x = e1v + EV[i >> 2][i & 3];                                    \
      float s = fmaxf(x, LRA * x);                                          \
      float p = (AV[i >> 2][i & 3] > 0) ? __expf(s) : 0.f;                  \
      rs += p; pf0[i] = f2bf(p);                                            \
    }                                                                       \
    _Pragma("unroll")                                                       \
    for (int i = 0; i < 8; ++i) {                                           \
      float x = e1v + EV[2 + (i >> 2)][i & 3];                              \
      float s = fmaxf(x, LRA * x);                                          \
      float p = (AV[2 + (i >> 2)][i & 3] > 0) ? __expf(s) : 0.f;            \
      rs += p; pf1[i] = f2bf(p);                                            \
    }                                                                       \
    {                                                                       \
      char* wb_ = (BUF) + prow * 512;                                       \
      const int sw_ = (prow & 7) << 4;                                      \
      *(bf16x8*)(wb_ + ((psub * 16) ^ sw_)) = pf0;                          \
      *(bf16x8*)(wb_ + ((256 + psub * 16) ^ sw_)) = pf1;                    \
    }                                                                       \
    __syncthreads();                                                        \
    _Pragma("unroll")                                                       \
    for (int kt = 0; kt < 8; ++kt) {                                        \
      const int boff_ = (kt * 64 + lq * 16) ^ ((lr & 7) << 4);              \
      bf16x8 a0 = *(const bf16x8*)((BUF) + lr * 512 + boff_);               \
      bf16x8 a1 = *(const bf16x8*)((BUF) + (16 + lr) * 512 + boff_);        \
      const short* bp_ = WhT + (J0) + kt * 32 + lq * 8;                     \
      bf16x8 b0 = *(const bf16x8*)(bp_ + bcol0);                            \
      bf16x8 b1 = *(const bf16x8*)(bp_ + bcol1);                            \
      acc[0][0] = __builtin_amdgcn_mfma_f32_16x16x32_bf16(a0, b0, acc[0][0], 0, 0, 0); \
      acc[1][0] = __builtin_amdgcn_mfma_f32_16x16x32_bf16(a1, b0, acc[1][0], 0, 0, 0); \
      acc[0][1] = __builtin_amdgcn_mfma_f32_16x16x32_bf16(a0, b1, acc[0][1], 0, 0, 0); \
      acc[1][1] = __builtin_amdgcn_mfma_f32_16x16x32_bf16(a1, b1, acc[1][1], 0, 0, 0); \
    }                                                                       \
  }

__global__ __launch_bounds__(512) void k3_old(const int* __restrict__ adj,
                                              const float* __restrict__ e1,
                                              const float* __restrict__ e2,
                                              const short* __restrict__ WhT,
                                              float* __restrict__ out) {
  __shared__ __align__(16) char Plds[2][32 * 512];
  __shared__ float rowsum[32];
  const int r0 = blockIdx.x * 32;
  const int t = threadIdx.x;
  const int w = t >> 6, l = t & 63;
  const int lr = l & 15, lq = l >> 4;
  const int prow = t >> 4;
  const int psub = t & 15;
  const int jb = psub * 8;
  const int gr = r0 + prow;
  const bool rowok = (gr < NN);
  const float e1v = rowok ? e1[gr] : 0.f;
  const size_t adjrow = (size_t)gr * NN;
  const size_t bcol0 = (size_t)(w * 32 + lr) * NPAD;
  const size_t bcol1 = (size_t)(w * 32 + 16 + lr) * NPAD;
  float rs = 0.f;
  f32x4 acc[2][2];
#pragma unroll
  for (int m = 0; m < 2; ++m)
#pragma unroll
    for (int n = 0; n < 2; ++n)
#pragma unroll
      for (int q = 0; q < 4; ++q) acc[m][n][q] = 0.f;

  const int NT = (NN + 255) / 256;
  i32x4 avA[4], avB[4];
  f32x4 evA[4], evB[4];
  OLD_LOAD(0, avA, evA);
  for (int jt = 0; jt < NT; jt += 2) {
    OLD_LOAD((jt + 1) * 256, avB, evB);
    OLD_PHASE(jt * 256, avA, evA, &Plds[0][0]);
    if (jt + 2 < NT) OLD_LOAD((jt + 2) * 256, avA, evA);
    OLD_PHASE((jt + 1) * 256, avB, evB, &Plds[1][0]);
  }
  rs += __shfl_xor(rs, 1); rs += __shfl_xor(rs, 2);
  rs += __shfl_xor(rs, 4); rs += __shfl_xor(rs, 8);
  if (psub == 0) rowsum[prow] = rs;
  __syncthreads();
#pragma unroll
  for (int m = 0; m < 2; ++m)
#pragma unroll
    for (int n = 0; n < 2; ++n)
#pragma unroll
      for (int q = 0; q < 4; ++q) {
        int row = m * 16 + lq * 4 + q;
        int grow = r0 + row;
        if (grow < NN) {
          float v = acc[m][n][q] / rowsum[row];
          float o = (v > 0.f) ? v : (__expf(v) - 1.f);
          out[(size_t)grow * FOUT + w * 32 + n * 16 + lr] = o;
        }
      }
}

extern "C" void kernel_launch(void* const* d_in, const int* in_sizes, int n_in,
                              void* d_out, int out_size, void* d_ws, size_t ws_size,
                              hipStream_t stream) {
  const float* h   = (const float*)d_in[0];
  const int*   adj = (const int*)d_in[1];
  const float* W   = (const float*)d_in[2];
  const float* a   = (const float*)d_in[3];
  float* out = (float*)d_out;
  char* ws = (char*)d_ws;
  _Float16* Wt  = (_Float16*)(ws + 0);            // 262144
  short*    WhT = (short*)(ws + 10502144);        // -> 15745024 (Wh slot unused now)
  float*    e1  = (float*)(ws + 15745024);        // -> 15785984
  float*    e2  = (float*)(ws + 15785984);        // -> 15826944
  unsigned* bits32 = (unsigned*)(ws + 15826944);  // 13107200 -> 28934144
  float*    pden = (float*)(ws + 28934144);       // 655360 -> 29589504
  short*    pnum = (short*)(ws + 29589504);       // 83886080 -> 113475584
  (void)in_sizes; (void)n_in; (void)out_size;

  const bool big = ws_size >= (size_t)113475584;

  k0_wt<<<dim3(512), dim3(256), 0, stream>>>(W, Wt);
  k12_fused<<<dim3(160), dim3(256), 0, stream>>>(h, Wt, a, e1, e2, WhT);

  if (big) {
    kp_bits<<<dim3(2048), dim3(256), 0, stream>>>(adj, bits32);
    k3_part<<<dim3((NPAD / 128) * NSL), dim3(512), 0, stream>>>(
        bits32, e1, e2, WhT, pnum, pden);
    k4_out<<<dim3(2500), dim3(256), 0, stream>>>(pnum, pden, out);
  } else {
    k3_old<<<dim3(313), dim3(512), 0, stream>>>(adj, e1, e2, WhT, out);
  }
}

// Round 15
// 244.478 us; speedup vs baseline: 1.4649x; 1.4649x over previous
//
#include <hip/hip_runtime.h>
#include <hip/hip_bf16.h>
#include <hip/hip_fp16.h>

#define NN    10000
#define FIN   512
#define FOUT  256
#define NPAD  10240
#define LRA   0.2f
#define NSL   16          // slices; id%16 -> 2 slices/XCD, B L2-resident
#define JLEN  640         // NPAD / NSL
#define NPH   10          // JLEN / 64
#define WPR32 320         // u32 words per row (LINEAR layout: word=j/32, bit=j%32)
#define KPBLK 12800       // kp blocks = NPAD*WPR32/256

typedef __attribute__((ext_vector_type(4))) float    f32x4;
typedef __attribute__((ext_vector_type(4))) int      i32x4;
typedef __attribute__((ext_vector_type(4))) short    s16x4;
typedef __attribute__((ext_vector_type(8))) _Float16 f16x8;
typedef __attribute__((ext_vector_type(8))) short    bf16x8;

static __device__ __forceinline__ short f2bf(float x) {
  unsigned u = __builtin_bit_cast(unsigned, x);
  u += 0x7fffu + ((u >> 16) & 1u);   // RNE; x always finite here
  return (short)(u >> 16);
}
static __device__ __forceinline__ float bf2f(short s) {
  unsigned u = ((unsigned)(unsigned short)s) << 16;
  return __builtin_bit_cast(float, u);
}

// ---------------- K0: Wt[c][k] = f16(W[k][c]) ----------------
__global__ __launch_bounds__(256) void k0_wt(const float* __restrict__ W,
                                             _Float16* __restrict__ Wt) {
  int idx = blockIdx.x * 256 + threadIdx.x;
  int k = idx >> 8, c = idx & 255;
  Wt[(size_t)c * FIN + k] = (_Float16)W[(size_t)k * FOUT + c];
}

// ---------------- KF: fused front — blocks [0,160): k12 (Wh->e1/e2/WhT);
// blocks [160,160+KPBLK): kp bit-pack (R13 version, plain cached loads).
// kp is HBM-read-bound, k12 is MFMA/LDS-bound -> concurrent, k12 hides under kp.
__global__ __launch_bounds__(256) void kf_front(const float* __restrict__ h,
                                                const _Float16* __restrict__ Wt,
                                                const float* __restrict__ a,
                                                float* __restrict__ e1,
                                                float* __restrict__ e2,
                                                short* __restrict__ WhT,
                                                const int* __restrict__ adj,
                                                unsigned* __restrict__ bits32) {
  __shared__ float tile[64][257];
  const int t = threadIdx.x;

  if (blockIdx.x >= 160) {
    // ---- kp path (exact R13 kp_bits) ----
    const int g = (blockIdx.x - 160) * 256 + t;    // word index, < NPAD*WPR32
    const int row = g / WPR32;
    const int wc = g - row * WPR32;
    if (row >= NN) { bits32[g] = 0u; return; }
    const int j0 = wc * 32;
    unsigned m = 0u;
    if (j0 + 32 <= NN) {
      const int* p = adj + (size_t)row * NN + j0;
      i32x4 v[8];
#pragma unroll
      for (int q = 0; q < 8; ++q) v[q] = *(const i32x4*)(p + q * 4);  // 8 in flight
#pragma unroll
      for (int q = 0; q < 8; ++q)
#pragma unroll
        for (int i = 0; i < 4; ++i)
          m |= (v[q][i] > 0 ? 1u : 0u) << (q * 4 + i);
    } else if (j0 < NN) {
      const int nv = NN - j0;
      const int* p = adj + (size_t)row * NN + j0;
      for (int k = 0; k < nv; ++k) m |= (p[k] > 0 ? 1u : 0u) << k;
    }
    bits32[g] = m;
    return;
  }

  // ---- k12 path ----
  const int r0 = blockIdx.x * 64;
  const int w = t >> 6, l = t & 63;
  const int lr = l & 15, lq = l >> 4;
  f32x4 acc[4][4];
#pragma unroll
  for (int m = 0; m < 4; ++m)
#pragma unroll
    for (int n = 0; n < 4; ++n)
#pragma unroll
      for (int q = 0; q < 4; ++q) acc[m][n][q] = 0.f;

  for (int kk = 0; kk < FIN; kk += 32) {
    f16x8 af[4];
#pragma unroll
    for (int m = 0; m < 4; ++m) {
      int gr = r0 + m * 16 + lr;
      if (gr < NN) {
        const f32x4* p = (const f32x4*)(h + (size_t)gr * FIN + kk + lq * 8);
        f32x4 v0 = p[0], v1 = p[1];
#pragma unroll
        for (int i = 0; i < 4; ++i) { af[m][i] = (_Float16)v0[i]; af[m][i + 4] = (_Float16)v1[i]; }
      } else {
#pragma unroll
        for (int i = 0; i < 8; ++i) af[m][i] = (_Float16)0.f;
      }
    }
#pragma unroll
    for (int n = 0; n < 4; ++n) {
      int gc = w * 64 + n * 16 + lr;
      f16x8 bf = *(const f16x8*)(Wt + (size_t)gc * FIN + kk + lq * 8);
#pragma unroll
      for (int m = 0; m < 4; ++m)
        acc[m][n] = __builtin_amdgcn_mfma_f32_16x16x32_f16(af[m], bf, acc[m][n], 0, 0, 0);
    }
  }
#pragma unroll
  for (int m = 0; m < 4; ++m)
#pragma unroll
    for (int n = 0; n < 4; ++n)
#pragma unroll
      for (int q = 0; q < 4; ++q)
        tile[m * 16 + lq * 4 + q][w * 64 + n * 16 + lr] = acc[m][n][q];
  __syncthreads();
  {
    int r = t >> 2, sub = t & 3;
    float s1 = 0.f, s2 = 0.f;
#pragma unroll
    for (int i = 0; i < 64; ++i) {
      int c = sub + 4 * i;
      float v = tile[r][c];
      s1 += v * a[c];
      s2 += v * a[FOUT + c];
    }
    s1 += __shfl_xor(s1, 1); s1 += __shfl_xor(s1, 2);
    s2 += __shfl_xor(s2, 1); s2 += __shfl_xor(s2, 2);
    if (sub == 0) { e1[r0 + r] = s1; e2[r0 + r] = s2; }   // pad rows: tile==0 -> 0
  }
#pragma unroll
  for (int c0 = 0; c0 < FOUT; c0 += 64)
#pragma unroll
    for (int i = 0; i < 16; ++i) {
      int e = t + 256 * i;
      int c = e >> 6, rr = e & 63;
      WhT[(size_t)(c0 + c) * NPAD + r0 + rr] = f2bf(tile[rr][c0 + c]);
    }
}

// ---------------- K3: partial masked-softmax @ Wh (R13 structure) ----------
#define MFMA_B(AV, BV, ACC) ACC = __builtin_amdgcn_mfma_f32_16x16x32_bf16(AV, BV, ACC, 0, 0, 0)

#define B_ISSUE(PH)                                                           \
  {                                                                           \
    const int jg_ = jbase + (PH) * 64 + lq * 8;                               \
    bv00 = *(const bf16x8*)(WhT + bcol0 + jg_);                               \
    bv01 = *(const bf16x8*)(WhT + bcol1 + jg_);                               \
    bv10 = *(const bf16x8*)(WhT + bcol0 + jg_ + 32);                          \
    bv11 = *(const bf16x8*)(WhT + bcol1 + jg_ + 32);                          \
  }

#define PRODUCE(PH)                                                           \
  {                                                                           \
    const int jl_ = (PH) * 64 + sub * 16;                                     \
    f32x4 ea = *(const f32x4*)(e2s + jl_);                                    \
    f32x4 eb = *(const f32x4*)(e2s + jl_ + 4);                                \
    f32x4 ec = *(const f32x4*)(e2s + jl_ + 8);                                \
    f32x4 ed = *(const f32x4*)(e2s + jl_ + 12);                               \
    const unsigned m16 = mk[(PH) >> 1] >> (((PH) & 1) * 16);                  \
    bf16x8 pf0, pf1;                                                          \
    _Pragma("unroll")                                                         \
    for (int i = 0; i < 16; ++i) {                                            \
      float x = e1v + ((i < 4) ? ea[i & 3] : (i < 8) ? eb[i & 3]              \
                       : (i < 12) ? ec[i & 3] : ed[i & 3]);                   \
      float sv = fmaxf(x, LRA * x);                                           \
      float p = ((m16 >> i) & 1u) ? __expf(sv) : 0.f;                         \
      rs += p;                                                                \
      if (i < 8) pf0[i] = f2bf(p); else pf1[i & 7] = f2bf(p);                 \
    }                                                                         \
    char* wb_ = &Plds[(PH) & 1][0] + prow * 128;                              \
    *(bf16x8*)(wb_ + ((sub * 32) ^ psw)) = pf0;                               \
    *(bf16x8*)(wb_ + ((sub * 32 + 16) ^ psw)) = pf1;                          \
  }

#define CONSUME(PH)                                                           \
  {                                                                           \
    const char* pb_ = &Plds[(PH) & 1][0];                                     \
    __builtin_amdgcn_s_setprio(1);                                            \
    _Pragma("unroll")                                                         \
    for (int kt = 0; kt < 2; ++kt) {                                          \
      const int ao_ = (kt * 64 + lq * 16) ^ axor;                             \
      _Pragma("unroll")                                                       \
      for (int m = 0; m < 8; ++m) {                                           \
        bf16x8 av = *(const bf16x8*)(pb_ + m * 2048 + lr * 128 + ao_);        \
        MFMA_B(av, (kt ? bv10 : bv00), acc[m][0]);                            \
        MFMA_B(av, (kt ? bv11 : bv01), acc[m][1]);                            \
      }                                                                       \
    }                                                                         \
    __builtin_amdgcn_s_setprio(0);                                            \
  }

#define K3_ITER(PH)                                                           \
  __syncthreads();                                                            \
  B_ISSUE(PH);                                                                \
  PRODUCE((PH) + 1);                                                          \
  CONSUME(PH);

__global__ __launch_bounds__(512, 2) void k3_part(const unsigned* __restrict__ bits32,
                                                  const float* __restrict__ e1,
                                                  const float* __restrict__ e2,
                                                  const short* __restrict__ WhT,
                                                  short* __restrict__ pnum,
                                                  float* __restrict__ pden) {
  __shared__ __align__(16) char Plds[2][16384];   // [128 r][64 j] bf16, XOR-swizzled
  __shared__ float e2s[JLEN];
  const int id = blockIdx.x;
  const int s = id & (NSL - 1);
  const int r0 = (id >> 4) * 128;
  const int jbase = s * JLEN;
  const int t = threadIdx.x;
  const int w = t >> 6, l = t & 63;
  const int lr = l & 15, lq = l >> 4;
  const int prow = t >> 2, sub = t & 3;           // producer: 4 thr/row, 16 j each
  const int psw = (prow & 7) << 4;
  const int axor = (lr & 7) << 4;
  const int grow = r0 + prow;
  const float e1v = e1[grow];
  const size_t bcol0 = (size_t)(w * 32 + lr) * NPAD;
  const size_t bcol1 = bcol0 + (size_t)16 * NPAD;

  if (t < JLEN / 4) ((f32x4*)e2s)[t] = ((const f32x4*)(e2 + jbase))[t];

  unsigned mk[NPH / 2];
  {
    const unsigned* br = bits32 + (size_t)grow * WPR32 + (jbase >> 5) + (sub >> 1);
    const int hs = (sub & 1) * 16;
#pragma unroll
    for (int ph = 0; ph < NPH; ++ph) {
      unsigned m16 = (br[ph * 2] >> hs) & 0xFFFFu;
      if (ph & 1) mk[ph >> 1] |= m16 << 16; else mk[ph >> 1] = m16;
    }
  }

  f32x4 acc[8][2];
#pragma unroll
  for (int m = 0; m < 8; ++m)
#pragma unroll
    for (int n = 0; n < 2; ++n)
#pragma unroll
      for (int q = 0; q < 4; ++q) acc[m][n][q] = 0.f;
  float rs = 0.f;
  bf16x8 bv00, bv01, bv10, bv11;

  __syncthreads();                                 // e2s ready
  PRODUCE(0);
  K3_ITER(0) K3_ITER(1) K3_ITER(2) K3_ITER(3) K3_ITER(4)
  K3_ITER(5) K3_ITER(6) K3_ITER(7) K3_ITER(8)
  __syncthreads();
  B_ISSUE(9);
  CONSUME(9);

  rs += __shfl_xor(rs, 1); rs += __shfl_xor(rs, 2);
  if (sub == 0) pden[(size_t)s * NPAD + grow] = rs;
  {
    short* po = pnum + ((size_t)s * NPAD + r0) * FOUT;
#pragma unroll
    for (int m = 0; m < 8; ++m)
#pragma unroll
      for (int n = 0; n < 2; ++n)
#pragma unroll
        for (int q = 0; q < 4; ++q) {
          int row = m * 16 + lq * 4 + q;
          po[(size_t)row * FOUT + w * 32 + n * 16 + lr] = f2bf(acc[m][n][q]);
        }
  }
}

// ---------------- K4: reduce slices, normalize, elu (short4 loads) ----------
__global__ __launch_bounds__(256) void k4_out(const short* __restrict__ pnum,
                                              const float* __restrict__ pden,
                                              float* __restrict__ out) {
  const int t = threadIdx.x;
  const int row = blockIdx.x * 4 + (t >> 6);      // grid 2500, 4 rows/block
  const int c4 = (t & 63) * 4;
  float den = 0.f;
#pragma unroll
  for (int s = 0; s < NSL; ++s) den += pden[(size_t)s * NPAD + row];
  float n0 = 0.f, n1 = 0.f, n2 = 0.f, n3 = 0.f;
#pragma unroll
  for (int s = 0; s < NSL; ++s) {
    s16x4 v = *(const s16x4*)(pnum + ((size_t)s * NPAD + row) * FOUT + c4);
    n0 += bf2f(v[0]); n1 += bf2f(v[1]); n2 += bf2f(v[2]); n3 += bf2f(v[3]);
  }
  const float inv = 1.f / den;
  f32x4 o;
  float v0 = n0 * inv; o[0] = (v0 > 0.f) ? v0 : (__expf(v0) - 1.f);
  float v1 = n1 * inv; o[1] = (v1 > 0.f) ? v1 : (__expf(v1) - 1.f);
  float v2 = n2 * inv; o[2] = (v2 > 0.f) ? v2 : (__expf(v2) - 1.f);
  float v3 = n3 * inv; o[3] = (v3 > 0.f) ? v3 : (__expf(v3) - 1.f);
  *(f32x4*)(out + (size_t)row * FOUT + c4) = o;
}

// ---------------- Fallback (ws too small): R2 fused k3 ----------------
#define OLD_LOAD(J0N, AV, EV)                                               \
  {                                                                         \
    const int jn_ = (J0N) + jb;                                             \
    EV[0] = *(const f32x4*)(e2 + jn_);                                      \
    EV[1] = *(const f32x4*)(e2 + jn_ + 4);                                  \
    EV[2] = *(const f32x4*)(e2 + jn_ + 128);                                \
    EV[3] = *(const f32x4*)(e2 + jn_ + 132);                                \
    if (rowok && (J0N) + 256 <= NN) {                                       \
      AV[0] = *(const i32x4*)(adj + adjrow + jn_);                          \
      AV[1] = *(const i32x4*)(adj + adjrow + jn_ + 4);                      \
      AV[2] = *(const i32x4*)(adj + adjrow + jn_ + 128);                    \
      AV[3] = *(const i32x4*)(adj + adjrow + jn_ + 132);                    \
    } else {                                                                \
      _Pragma("unroll")                                                     \
      for (int p_ = 0; p_ < 4; ++p_) {                                      \
        _Pragma("unroll")                                                   \
        for (int i_ = 0; i_ < 4; ++i_) {                                    \
          int j_ = jn_ + (p_ >> 1) * 128 + (p_ & 1) * 4 + i_;               \
          AV[p_][i_] = (rowok && j_ < NN) ? adj[adjrow + j_] : 0;           \
        }                                                                   \
      }                                                                     \
    }                                                                       \
  }

#define OLD_PHASE(J0, AV, EV, BUF)                                          \
  {                                                                         \
    bf16x8 pf0, pf1;                                                        \
    _Pragma("unroll")                                                       \
    for (int i = 0; i < 8; ++i) {                                           \
      float x = e1v + EV[i >> 2][i & 3];                                    \
      float s = fmaxf(x, LRA * x);                                          \
      float p = (AV[i >> 2][i & 3] > 0) ? __expf(s) : 0.f;                  \
      rs += p; pf0[i] = f2bf(p);                                            \
    }                                                                       \
    _Pragma("unroll")                                                       \
    for (int i = 0; i < 8; ++i) {                                           \
      float x = e1v + EV[2 + (i >> 2)][i & 3];                              \
      float s = fmaxf(x, LRA * x);                                          \
      float p = (AV[2 + (i >> 2)][i & 3] > 0) ? __expf(s) : 0.f;            \
      rs += p; pf1[i] = f2bf(p);                                            \
    }                                                                       \
    {                                                                       \
      char* wb_ = (BUF) + prow * 512;                                       \
      const int sw_ = (prow & 7) << 4;                                      \
      *(bf16x8*)(wb_ + ((psub * 16) ^ sw_)) = pf0;                          \
      *(bf16x8*)(wb_ + ((256 + psub * 16) ^ sw_)) = pf1;                    \
    }                                                                       \
    __syncthreads();                                                        \
    _Pragma("unroll")                                                       \
    for (int kt = 0; kt < 8; ++kt) {                                        \
      const int boff_ = (kt * 64 + lq * 16) ^ ((lr & 7) << 4);              \
      bf16x8 a0 = *(const bf16x8*)((BUF) + lr * 512 + boff_);               \
      bf16x8 a1 = *(const bf16x8*)((BUF) + (16 + lr) * 512 + boff_);        \
      const short* bp_ = WhT + (J0) + kt * 32 + lq * 8;                     \
      bf16x8 b0 = *(const bf16x8*)(bp_ + bcol0);                            \
      bf16x8 b1 = *(const bf16x8*)(bp_ + bcol1);                            \
      acc[0][0] = __builtin_amdgcn_mfma_f32_16x16x32_bf16(a0, b0, acc[0][0], 0, 0, 0); \
      acc[1][0] = __builtin_amdgcn_mfma_f32_16x16x32_bf16(a1, b0, acc[1][0], 0, 0, 0); \
      acc[0][1] = __builtin_amdgcn_mfma_f32_16x16x32_bf16(a0, b1, acc[0][1], 0, 0, 0); \
      acc[1][1] = __builtin_amdgcn_mfma_f32_16x16x32_bf16(a1, b1, acc[1][1], 0, 0, 0); \
    }                                                                       \
  }

__global__ __launch_bounds__(512) void k3_old(const int* __restrict__ adj,
                                              const float* __restrict__ e1,
                                              const float* __restrict__ e2,
                                              const short* __restrict__ WhT,
                                              float* __restrict__ out) {
  __shared__ __align__(16) char Plds[2][32 * 512];
  __shared__ float rowsum[32];
  const int r0 = blockIdx.x * 32;
  const int t = threadIdx.x;
  const int w = t >> 6, l = t & 63;
  const int lr = l & 15, lq = l >> 4;
  const int prow = t >> 4;
  const int psub = t & 15;
  const int jb = psub * 8;
  const int gr = r0 + prow;
  const bool rowok = (gr < NN);
  const float e1v = rowok ? e1[gr] : 0.f;
  const size_t adjrow = (size_t)gr * NN;
  const size_t bcol0 = (size_t)(w * 32 + lr) * NPAD;
  const size_t bcol1 = (size_t)(w * 32 + 16 + lr) * NPAD;
  float rs = 0.f;
  f32x4 acc[2][2];
#pragma unroll
  for (int m = 0; m < 2; ++m)
#pragma unroll
    for (int n = 0; n < 2; ++n)
#pragma unroll
      for (int q = 0; q < 4; ++q) acc[m][n][q] = 0.f;

  const int NT = (NN + 255) / 256;
  i32x4 avA[4], avB[4];
  f32x4 evA[4], evB[4];
  OLD_LOAD(0, avA, evA);
  for (int jt = 0; jt < NT; jt += 2) {
    OLD_LOAD((jt + 1) * 256, avB, evB);
    OLD_PHASE(jt * 256, avA, evA, &Plds[0][0]);
    if (jt + 2 < NT) OLD_LOAD((jt + 2) * 256, avA, evA);
    OLD_PHASE((jt + 1) * 256, avB, evB, &Plds[1][0]);
  }
  rs += __shfl_xor(rs, 1); rs += __shfl_xor(rs, 2);
  rs += __shfl_xor(rs, 4); rs += __shfl_xor(rs, 8);
  if (psub == 0) rowsum[prow] = rs;
  __syncthreads();
#pragma unroll
  for (int m = 0; m < 2; ++m)
#pragma unroll
    for (int n = 0; n < 2; ++n)
#pragma unroll
      for (int q = 0; q < 4; ++q) {
        int row = m * 16 + lq * 4 + q;
        int grow = r0 + row;
        if (grow < NN) {
          float v = acc[m][n][q] / rowsum[row];
          float o = (v > 0.f) ? v : (__expf(v) - 1.f);
          out[(size_t)grow * FOUT + w * 32 + n * 16 + lr] = o;
        }
      }
}

extern "C" void kernel_launch(void* const* d_in, const int* in_sizes, int n_in,
                              void* d_out, int out_size, void* d_ws, size_t ws_size,
                              hipStream_t stream) {
  const float* h   = (const float*)d_in[0];
  const int*   adj = (const int*)d_in[1];
  const float* W   = (const float*)d_in[2];
  const float* a   = (const float*)d_in[3];
  float* out = (float*)d_out;
  char* ws = (char*)d_ws;
  _Float16* Wt  = (_Float16*)(ws + 0);            // 262144
  short*    WhT = (short*)(ws + 10502144);        // -> 15745024
  float*    e1  = (float*)(ws + 15745024);        // -> 15785984
  float*    e2  = (float*)(ws + 15785984);        // -> 15826944
  unsigned* bits32 = (unsigned*)(ws + 15826944);  // 13107200 -> 28934144
  float*    pden = (float*)(ws + 28934144);       // 655360 -> 29589504
  short*    pnum = (short*)(ws + 29589504);       // 83886080 -> 113475584
  (void)in_sizes; (void)n_in; (void)out_size;

  const bool big = ws_size >= (size_t)113475584;

  k0_wt<<<dim3(512), dim3(256), 0, stream>>>(W, Wt);

  if (big) {
    kf_front<<<dim3(160 + KPBLK), dim3(256), 0, stream>>>(
        h, Wt, a, e1, e2, WhT, adj, bits32);
    k3_part<<<dim3((NPAD / 128) * NSL), dim3(512), 0, stream>>>(
        bits32, e1, e2, WhT, pnum, pden);
    k4_out<<<dim3(2500), dim3(256), 0, stream>>>(pnum, pden, out);
  } else {
    kf_front<<<dim3(160), dim3(256), 0, stream>>>(
        h, Wt, a, e1, e2, WhT, adj, bits32);
    k3_old<<<dim3(313), dim3(512), 0, stream>>>(adj, e1, e2, WhT, out);
  }
}